// Round 9
// baseline (491.876 us; speedup 1.0000x reference)
//
#include <hip/hip_runtime.h>

// Problem constants (B=2, S=2048, D_IN=2048, H=16, G=4, HD=128)
#define S_LEN 2048
#define NROWS 4096      // B*S
#define DIN   2048
#define DQKV  5120      // 4096 (q|gate) + 512 K + 512 V
#define DQG   4096

typedef __bf16 bf16x8 __attribute__((ext_vector_type(8)));
typedef float  floatx4 __attribute__((ext_vector_type(4)));
typedef unsigned short u16;

#define QK_SCALE 0.08838834764831845f   // 128^-0.5, folded into Q

__device__ __forceinline__ u16 f2bf(float f) {
  unsigned int u = __float_as_uint(f);
  u += 0x7fffu + ((u >> 16) & 1u);   // RNE
  return (u16)(u >> 16);
}
__device__ __forceinline__ float bf2f(u16 v) {
  return __uint_as_float(((unsigned int)v) << 16);
}
// XOR-8 chunk swizzle within each 64-element column group, keyed by row&7.
__device__ __forceinline__ int swz(int col, int row) {
  return (col & ~63) | ((((col >> 3) & 7) ^ (row & 7)) << 3) | (col & 7);
}

__device__ __forceinline__ void gload_lds16(const void* g, void* l) {
  __builtin_amdgcn_global_load_lds(
      (__attribute__((address_space(1))) void*)(void*)(g),
      (__attribute__((address_space(3))) void*)(l), 16, 0, 0);
}

// ---------------- merged preprocessing: x-cvt + 4 transposes (1 launch) ----------------
__device__ __forceinline__ void tcvt_body(const float* __restrict__ src,
                                          u16* __restrict__ dst,
                                          int C, int dld, int bx, int by,
                                          float (*tile)[33]) {
  const int c0 = bx * 32, r0 = by * 32;
  const int t = threadIdx.x;
  {
    const int rl = t >> 3, cl4 = (t & 7) * 4;
    const float4 v = *reinterpret_cast<const float4*>(src + (size_t)(r0 + rl) * C + c0 + cl4);
    tile[rl][cl4 + 0] = v.x; tile[rl][cl4 + 1] = v.y;
    tile[rl][cl4 + 2] = v.z; tile[rl][cl4 + 3] = v.w;
  }
  __syncthreads();
  {
    const int cl = t >> 3, rl4 = (t & 7) * 4;
    ushort4 o;
    o.x = f2bf(tile[rl4 + 0][cl]); o.y = f2bf(tile[rl4 + 1][cl]);
    o.z = f2bf(tile[rl4 + 2][cl]); o.w = f2bf(tile[rl4 + 3][cl]);
    const int rd = c0 + cl, cd = r0 + rl4;      // dst (row, col)
    *reinterpret_cast<ushort4*>(dst + (size_t)rd * dld + swz(cd, rd)) = o;
  }
}

__global__ __launch_bounds__(256) void prep(const float* __restrict__ x,
                                            const float* __restrict__ Wq,
                                            const float* __restrict__ Wk,
                                            const float* __restrict__ Wv,
                                            const float* __restrict__ Wo,
                                            u16* __restrict__ xb,
                                            u16* __restrict__ WqkvT,
                                            u16* __restrict__ WoT) {
  __shared__ float tile[32][33];
  const int bid = blockIdx.x;
  if (bid < 8192) {                       // cvt_x
    const int i = bid * 256 + threadIdx.x;
    const int row = i >> 9, col = (i & 511) << 2;
    const float4 v = reinterpret_cast<const float4*>(x)[i];
    ushort4 o;
    o.x = f2bf(v.x); o.y = f2bf(v.y); o.z = f2bf(v.z); o.w = f2bf(v.w);
    *reinterpret_cast<ushort4*>(xb + (size_t)row * DIN + swz(col, row)) = o;
  } else if (bid < 16384) {               // Wq^T (2048x4096 -> rows 0..4095)
    const int l = bid - 8192;
    tcvt_body(Wq, WqkvT, 4096, 2048, l & 127, l >> 7, tile);
  } else if (bid < 17408) {               // Wk^T -> rows 4096..4607
    const int l = bid - 16384;
    tcvt_body(Wk, WqkvT + (size_t)4096 * 2048, 512, 2048, l & 15, l >> 4, tile);
  } else if (bid < 18432) {               // Wv^T -> rows 4608..5119
    const int l = bid - 17408;
    tcvt_body(Wv, WqkvT + (size_t)4608 * 2048, 512, 2048, l & 15, l >> 4, tile);
  } else {                                // Wo^T
    const int l = bid - 18432;
    tcvt_body(Wo, WoT, 2048, 2048, l & 63, l >> 6, tile);
  }
}

// ---------------- bf16 GEMM, 128x128 tile, BK=64 (K|V proj + Wo GEMM) ----------------
template <bool BF16_OUT>
__global__ __launch_bounds__(256) void gemm_bt(const u16* __restrict__ A,
                                               const u16* __restrict__ Bt,
                                               void* __restrict__ Cv,
                                               int M, int N, int K, int ldc) {
  __shared__ __align__(16) u16 As[128 * 64];
  __shared__ __align__(16) u16 Bs[128 * 64];
  const int tid = threadIdx.x, wv = tid >> 6, lane = tid & 63;
  const int m0 = blockIdx.y * 128, n0 = blockIdx.x * 128;
  const int wm = (wv >> 1) * 64, wn = (wv & 1) * 64;
  const int frow = lane & 15, quad = lane >> 4, fsw = frow & 7;
  const int srow = lane >> 3, scol = (lane & 7) * 8;
  floatx4 acc[4][4] = {};
  for (int k0 = 0; k0 < K; k0 += 64) {
#pragma unroll
    for (int i = 0; i < 4; ++i) {
      const int rr = (wv * 4 + i) * 8;
      gload_lds16(A  + (size_t)(m0 + rr + srow) * K + k0 + scol, &As[rr * 64]);
      gload_lds16(Bt + (size_t)(n0 + rr + srow) * K + k0 + scol, &Bs[rr * 64]);
    }
    __syncthreads();
#pragma unroll
    for (int ks = 0; ks < 2; ++ks) {
      bf16x8 af[4], bfr[4];
#pragma unroll
      for (int mi = 0; mi < 4; ++mi)
        af[mi] = *reinterpret_cast<const bf16x8*>(
            &As[(wm + mi * 16 + frow) * 64 + (((ks * 4 + quad) ^ fsw) << 3)]);
#pragma unroll
      for (int ni = 0; ni < 4; ++ni)
        bfr[ni] = *reinterpret_cast<const bf16x8*>(
            &Bs[(wn + ni * 16 + frow) * 64 + (((ks * 4 + quad) ^ fsw) << 3)]);
#pragma unroll
      for (int mi = 0; mi < 4; ++mi)
#pragma unroll
        for (int ni = 0; ni < 4; ++ni)
          acc[mi][ni] = __builtin_amdgcn_mfma_f32_16x16x32_bf16(af[mi], bfr[ni], acc[mi][ni], 0, 0, 0);
    }
    __syncthreads();
  }
  const int crow = (lane >> 4) * 4, ccol = lane & 15;
#pragma unroll
  for (int mi = 0; mi < 4; ++mi)
#pragma unroll
    for (int ni = 0; ni < 4; ++ni) {
      const size_t base = (size_t)(m0 + wm + mi * 16 + crow) * ldc + (n0 + wn + ni * 16 + ccol);
      if constexpr (BF16_OUT) {
        u16* C = (u16*)Cv;
#pragma unroll
        for (int r = 0; r < 4; ++r) C[base + (size_t)r * ldc] = f2bf(acc[mi][ni][r]);
      } else {
        float* C = (float*)Cv;
#pragma unroll
        for (int r = 0; r < 4; ++r) C[base + (size_t)r * ldc] = acc[mi][ni][r];
      }
    }
}

// ---------------- 8-phase deep-pipelined bf16 GEMM, 256x256 tile, BK=64 ----------------
// (unchanged — 84 µs / 34% MfmaUtil measured; held constant)
__global__ __launch_bounds__(512, 2) void gemm256(const u16* __restrict__ A,
                                                  const u16* __restrict__ Bt,
                                                  u16* __restrict__ C,
                                                  int K, int ldc) {
  __shared__ __align__(16) u16 As[2][256 * 64];   // 64 KiB
  __shared__ __align__(16) u16 Bs[2][256 * 64];   // 64 KiB
  const int tid = threadIdx.x, wv = tid >> 6, lane = tid & 63;
  const int nx = gridDim.x;
  const int orig = blockIdx.y * nx + blockIdx.x;
  const int cpx = (nx * gridDim.y) >> 3;
  const int wgid = (orig & 7) * cpx + (orig >> 3);
  const int m0 = (wgid / nx) * 256, n0 = (wgid % nx) * 256;
  const int wm = (wv >> 2) * 128, wn = (wv & 3) * 64;
  const int f = lane & 15, quad = lane >> 4, fs = f & 7;

  const u16* Ab = A  + (size_t)(m0 + wv * 8 + (lane >> 3)) * K + (lane & 7) * 8;
  const u16* Bb = Bt + (size_t)(n0 + wv * 8 + (lane >> 3)) * K + (lane & 7) * 8;

  floatx4 acc[8][4] = {};
  bf16x8 af[4], bfr[4];

  auto stageA = [&](int sl, int t, int u) {
    gload_lds16(Ab + (size_t)u * 64 * K + (size_t)t * 64, &As[sl][(u * 64 + wv * 8) * 64]);
  };
  auto stageB = [&](int sl, int t, int u) {
    gload_lds16(Bb + (size_t)u * 64 * K + (size_t)t * 64, &Bs[sl][(u * 64 + wv * 8) * 64]);
  };
  auto loadA = [&](int sl, int fh, int ks) {
#pragma unroll
    for (int mf = 0; mf < 4; ++mf)
      af[mf] = *reinterpret_cast<const bf16x8*>(
          &As[sl][(wm + fh * 64 + mf * 16 + f) * 64 + ((((ks << 2) + quad) ^ fs) << 3)]);
  };
  auto loadB = [&](int sl, int ks) {
#pragma unroll
    for (int nf = 0; nf < 4; ++nf)
      bfr[nf] = *reinterpret_cast<const bf16x8*>(
          &Bs[sl][(wn + nf * 16 + f) * 64 + ((((ks << 2) + quad) ^ fs) << 3)]);
  };
  auto mmas = [&](int fh) {
#pragma unroll
    for (int mf = 0; mf < 4; ++mf)
#pragma unroll
      for (int nf = 0; nf < 4; ++nf)
        acc[fh * 4 + mf][nf] = __builtin_amdgcn_mfma_f32_16x16x32_bf16(
            af[mf], bfr[nf], acc[fh * 4 + mf][nf], 0, 0, 0);
  };

#pragma unroll
  for (int u = 0; u < 4; ++u) stageA(0, 0, u);
#pragma unroll
  for (int u = 0; u < 4; ++u) stageB(0, 0, u);
  stageA(1, 1, 0); stageA(1, 1, 2); stageB(1, 1, 0);
  asm volatile("s_waitcnt vmcnt(3)" ::: "memory");
  __builtin_amdgcn_s_barrier();

  const int IT = K >> 7;
#pragma unroll 1
  for (int i = 0; i < IT; ++i) {
    const int t0 = 2 * i;
    const bool st = (i < IT - 1);
    loadA(0, 0, 0); loadB(0, 0);
    stageA(1, t0 + 1, 1); stageA(1, t0 + 1, 3); stageB(1, t0 + 1, 1);
    __builtin_amdgcn_s_barrier();
    asm volatile("s_waitcnt lgkmcnt(0)" ::: "memory");
    __builtin_amdgcn_s_setprio(1); mmas(0); __builtin_amdgcn_s_setprio(0);
    __builtin_amdgcn_s_barrier();
    loadA(0, 1, 0);
    stageB(1, t0 + 1, 2); stageB(1, t0 + 1, 3);
    __builtin_amdgcn_s_barrier();
    asm volatile("s_waitcnt lgkmcnt(0)" ::: "memory");
    __builtin_amdgcn_s_setprio(1); mmas(1); __builtin_amdgcn_s_setprio(0);
    __builtin_amdgcn_s_barrier();
    loadA(0, 0, 1); loadB(0, 1);
    __builtin_amdgcn_s_barrier();
    asm volatile("s_waitcnt lgkmcnt(0)" ::: "memory");
    __builtin_amdgcn_s_setprio(1); mmas(0); __builtin_amdgcn_s_setprio(0);
    __builtin_amdgcn_s_barrier();
    loadA(0, 1, 1);
    if (st) { stageA(0, t0 + 2, 0); stageA(0, t0 + 2, 2); stageB(0, t0 + 2, 0); }
    __builtin_amdgcn_s_barrier();
    asm volatile("s_waitcnt lgkmcnt(0)" ::: "memory");
    __builtin_amdgcn_s_setprio(1); mmas(1); __builtin_amdgcn_s_setprio(0);
    if (st) { asm volatile("s_waitcnt vmcnt(3)" ::: "memory"); }
    else    { asm volatile("s_waitcnt vmcnt(0)" ::: "memory"); }
    __builtin_amdgcn_s_barrier();
    loadA(1, 0, 0); loadB(1, 0);
    if (st) { stageA(0, t0 + 2, 1); stageA(0, t0 + 2, 3); stageB(0, t0 + 2, 1); }
    __builtin_amdgcn_s_barrier();
    asm volatile("s_waitcnt lgkmcnt(0)" ::: "memory");
    __builtin_amdgcn_s_setprio(1); mmas(0); __builtin_amdgcn_s_setprio(0);
    __builtin_amdgcn_s_barrier();
    loadA(1, 1, 0);
    if (st) { stageB(0, t0 + 2, 2); stageB(0, t0 + 2, 3); }
    __builtin_amdgcn_s_barrier();
    asm volatile("s_waitcnt lgkmcnt(0)" ::: "memory");
    __builtin_amdgcn_s_setprio(1); mmas(1); __builtin_amdgcn_s_setprio(0);
    __builtin_amdgcn_s_barrier();
    loadA(1, 0, 1); loadB(1, 1);
    __builtin_amdgcn_s_barrier();
    asm volatile("s_waitcnt lgkmcnt(0)" ::: "memory");
    __builtin_amdgcn_s_setprio(1); mmas(0); __builtin_amdgcn_s_setprio(0);
    __builtin_amdgcn_s_barrier();
    loadA(1, 1, 1);
    if (st) { stageA(1, t0 + 3, 0); stageA(1, t0 + 3, 2); stageB(1, t0 + 3, 0); }
    __builtin_amdgcn_s_barrier();
    asm volatile("s_waitcnt lgkmcnt(0)" ::: "memory");
    __builtin_amdgcn_s_setprio(1); mmas(1); __builtin_amdgcn_s_setprio(0);
    if (st) { asm volatile("s_waitcnt vmcnt(3)" ::: "memory"); }
    __builtin_amdgcn_s_barrier();
  }

#pragma unroll
  for (int mf = 0; mf < 8; ++mf)
#pragma unroll
    for (int nf = 0; nf < 4; ++nf) {
      const size_t base = (size_t)(m0 + wm + (mf >> 2) * 64 + (mf & 3) * 16 + quad * 4) * ldc
                        + (n0 + wn + nf * 16 + f);
#pragma unroll
      for (int r = 0; r < 4; ++r) C[base + (size_t)r * ldc] = f2bf(acc[mf][nf][r]);
    }
}

// ---------------- merged post-projection: qnorm_rope + knorm_rope + vtrans (1 launch) ----------------
__global__ __launch_bounds__(256) void postproj(const u16* __restrict__ QKV,
                                                const float* __restrict__ qw,
                                                const float* __restrict__ kw,
                                                const float* __restrict__ cosT,
                                                const float* __restrict__ sinT,
                                                u16* __restrict__ Qb,
                                                u16* __restrict__ Kb,
                                                u16* __restrict__ Vt) {
  __shared__ u16 tile[32][40];
  const int bid = blockIdx.x;
  const int wv = threadIdx.x >> 6, lane = threadIdx.x & 63;
  if (bid < 16384) {                      // qnorm_rope
    const int idx = bid * 4 + wv;
    const int h = idx & 15, row = idx >> 4;
    const int s = row & (S_LEN - 1), b = row >> 11;
    const u16* base = QKV + (size_t)row * DQKV + h * 256;
    const float v0 = bf2f(base[lane]), v1 = bf2f(base[lane + 64]);
    float ss = v0 * v0 + v1 * v1;
#pragma unroll
    for (int m = 32; m >= 1; m >>= 1) ss += __shfl_xor(ss, m);
    const float rn = rsqrtf(ss * (1.0f / 128.0f) + 1e-6f) * QK_SCALE;
    const float n0 = v0 * rn * (1.0f + qw[lane]);
    const float n1 = v1 * rn * (1.0f + qw[lane + 64]);
    const float c0 = cosT[(size_t)s * 128 + lane], c1 = cosT[(size_t)s * 128 + lane + 64];
    const float sn0 = sinT[(size_t)s * 128 + lane], sn1 = sinT[(size_t)s * 128 + lane + 64];
    u16* qb = Qb + ((size_t)(b * 16 + h) * S_LEN + s) * 128;
    qb[lane]      = f2bf(n0 * c0 - n1 * sn0);
    qb[lane + 64] = f2bf(n1 * c1 + n0 * sn1);
  } else if (bid < 20480) {               // knorm_rope
    const int idx = (bid - 16384) * 4 + wv;
    const int g = idx & 3, row = idx >> 2;
    const int s = row & (S_LEN - 1), b = row >> 11;
    const u16* base = QKV + (size_t)row * DQKV + DQG + g * 128;
    const float v0 = bf2f(base[lane]), v1 = bf2f(base[lane + 64]);
    float ss = v0 * v0 + v1 * v1;
#pragma unroll
    for (int m = 32; m >= 1; m >>= 1) ss += __shfl_xor(ss, m);
    const float rn = rsqrtf(ss * (1.0f / 128.0f) + 1e-6f);
    const float n0 = v0 * rn * (1.0f + kw[lane]);
    const float n1 = v1 * rn * (1.0f + kw[lane + 64]);
    const float c0 = cosT[(size_t)s * 128 + lane], c1 = cosT[(size_t)s * 128 + lane + 64];
    const float sn0 = sinT[(size_t)s * 128 + lane], sn1 = sinT[(size_t)s * 128 + lane + 64];
    u16* kb = Kb + ((size_t)(b * 4 + g) * S_LEN + s) * 128;
    const int sw = s & 7;
    const int d0 = lane, d1 = lane + 64;
    const int p0 = (((d0 >> 3) ^ sw) << 3) | (d0 & 7);
    const int p1 = (((d1 >> 3) ^ sw) << 3) | (d1 & 7);
    kb[p0] = f2bf(n0 * c0 - n1 * sn0);
    kb[p1] = f2bf(n1 * c1 + n0 * sn1);
  } else {                                // vtrans
    const int l = bid - 20480;
    const int bg = l >> 8, rem = l & 255;
    const int d0 = ((rem >> 6) & 3) * 32, s0 = (rem & 63) * 32;
    const int b = bg >> 2, g = bg & 3;
    const int t = threadIdx.x;
    {
      const int sl = t >> 3, dl4 = (t & 7) * 4;
      const ushort4 v = *reinterpret_cast<const ushort4*>(
          QKV + (size_t)(b * S_LEN + s0 + sl) * DQKV + DQG + 512 + g * 128 + d0 + dl4);
      tile[sl][dl4 + 0] = v.x; tile[sl][dl4 + 1] = v.y;
      tile[sl][dl4 + 2] = v.z; tile[sl][dl4 + 3] = v.w;
    }
    __syncthreads();
    {
      const int dl = t >> 3, sl4 = (t & 7) * 4;
      ushort4 o;
      o.x = tile[sl4 + 0][dl]; o.y = tile[sl4 + 1][dl];
      o.z = tile[sl4 + 2][dl]; o.w = tile[sl4 + 3][dl];
      const int d = d0 + dl, s = s0 + sl4;
      const size_t base = (size_t)(bg * 128 + d) * S_LEN + (s & ~63);
      const int pos = ((((s >> 3) & 7) ^ (d & 7)) << 3) | (s & 7);
      *reinterpret_cast<ushort4*>(Vt + base + pos) = o;
    }
  }
}

// ---------------- MFMA flash attention + gating (paired-q, swapped QK^T) ----------------
// Each block processes BOTH q-tiles qtA=ip (0..15) and qtB=31-ip (16..31) in ONE
// K/V sweep over tiles 0..qtB: staged tiles 33 -> 32-ip (avg 24.5, -26%), and on
// the shared range kt<=qtA one bk/bv ds_read feeds TWO MFMAs (A and B). The
// t<=qtA branch is block-uniform. Keeps swapped QK^T (P-row lane-local, b64
// P-writes) and stage-before-compute dbuf with one vmcnt(0)+barrier per tile.
// LDS 80 KiB -> 2 blocks/CU.
__global__ __launch_bounds__(256) void attn(const u16* __restrict__ Qb,
                                            const u16* __restrict__ Kb,
                                            const u16* __restrict__ Vt,
                                            const u16* __restrict__ QKV,
                                            u16* __restrict__ ctxg) {
  __shared__ __align__(16) u16 Ks[2][64 * 128];   // [slot][key][d], chunk-swizzled
  __shared__ __align__(16) u16 Vts[2][128 * 64];  // [slot][d][key], chunk-swizzled
  __shared__ __align__(16) u16 Ps[4][2][16 * 64]; // per-wave P, [qsel][q=f][key]
  const int tid = threadIdx.x, wv = tid >> 6, lane = tid & 63;
  const int ip = blockIdx.x, bh = blockIdx.y;
  const int b = bh >> 4, h = bh & 15, g = h >> 2, bg = b * 4 + g;
  const int f = lane & 15, quad = lane >> 4, fq = quad * 8;
  const int fsw = f & 7;
  const u16* Kp = Kb + (size_t)bg * S_LEN * 128;
  const u16* Vp = Vt + (size_t)bg * 128 * S_LEN;
  u16* PwA = Ps[wv][0];
  u16* PwB = Ps[wv][1];
  const int pwr_base = f * 64 + ((quad & 1) << 2);
  const int pf0_off = f * 64 + ((quad ^ fsw) << 3);
  const int pf1_off = f * 64 + (((4 + quad) ^ fsw) << 3);

  auto stage_k = [&](int sl, int kt) {
    const int k0 = kt * 64;
#pragma unroll
    for (int i = 0; i < 4; ++i) {
      const int j = wv * 4 + i;
      gload_lds16(Kp + (size_t)k0 * 128 + j * 512 + lane * 8, &Ks[sl][j * 512]);
    }
  };
  auto stage_v = [&](int sl, int kt) {
    const int k0 = kt * 64;
#pragma unroll
    for (int i = 0; i < 4; ++i) {
      const int r0 = (wv * 4 + i) * 8;
      gload_lds16(Vp + (size_t)(r0 + (lane >> 3)) * S_LEN + k0 + (lane & 7) * 8,
                  &Vts[sl][r0 * 64]);
    }
  };

  const int qtA = ip, qtB = 31 - ip;          // qtB >= 16 > qtA
  const int nkt = qtB + 1;
  const int qrowA = qtA * 64 + wv * 16 + f;
  const int qrowB = qtB * 64 + wv * 16 + f;
  const u16* QpA = Qb + ((size_t)bh * S_LEN + qtA * 64 + wv * 16) * 128;
  const u16* QpB = Qb + ((size_t)bh * S_LEN + qtB * 64 + wv * 16) * 128;
  bf16x8 aqA[4], aqB[4];
#pragma unroll
  for (int c = 0; c < 4; ++c) {
    aqA[c] = *reinterpret_cast<const bf16x8*>(&QpA[(size_t)f * 128 + c * 32 + fq]);
    aqB[c] = *reinterpret_cast<const bf16x8*>(&QpB[(size_t)f * 128 + c * 32 + fq]);
  }

  floatx4 oA[8] = {}, oB[8] = {};
  float lsA = 0.f, lsB = 0.f;

  // prologue: stage tile 0
  stage_k(0, 0); stage_v(0, 0);
  asm volatile("s_waitcnt vmcnt(0)" ::: "memory");
  __syncthreads();

  int cur = 0;
  for (int t = 0; t < nkt; ++t) {
    const bool doA = (t <= qtA);            // block-uniform
    if (t + 1 < nkt) { stage_k(cur ^ 1, t + 1); stage_v(cur ^ 1, t + 1); }
    const int kb = t * 64;

    // QK^T: one bk load feeds both q-tiles
    {
      floatx4 scB[4] = {}, scA[4] = {};
#pragma unroll
      for (int c = 0; c < 4; ++c)
#pragma unroll
        for (int n = 0; n < 4; ++n) {
          bf16x8 bk = *reinterpret_cast<const bf16x8*>(
              &Ks[cur][(n * 16 + f) * 128 + (((4 * c + quad) ^ fsw) << 3)]);
          scB[n] = __builtin_amdgcn_mfma_f32_16x16x32_bf16(bk, aqB[c], scB[n], 0, 0, 0);
          if (doA)
            scA[n] = __builtin_amdgcn_mfma_f32_16x16x32_bf16(bk, aqA[c], scA[n], 0, 0, 0);
        }
      // softmax + P store (B always, A when valid)
#pragma unroll
      for (int n = 0; n < 4; ++n) {
        float pv_[4];
#pragma unroll
        for (int r = 0; r < 4; ++r) {
          const int key = kb + n * 16 + quad * 4 + r;
          const float p = (key <= qrowB) ? __expf(scB[n][r]) : 0.f;
          lsB += p; pv_[r] = p;
        }
        ushort4 pk;
        pk.x = f2bf(pv_[0]); pk.y = f2bf(pv_[1]); pk.z = f2bf(pv_[2]); pk.w = f2bf(pv_[3]);
        *reinterpret_cast<ushort4*>(
            &PwB[pwr_base + (((2 * n + (quad >> 1)) ^ fsw) << 3)]) = pk;
      }
      if (doA) {
#pragma unroll
        for (int n = 0; n < 4; ++n) {
          float pv_[4];
#pragma unroll
          for (int r = 0; r < 4; ++r) {
            const int key = kb + n * 16 + quad * 4 + r;
            const float p = (key <= qrowA) ? __expf(scA[n][r]) : 0.f;
            lsA += p; pv_[r] = p;
          }
          ushort4 pk;
          pk.x = f2bf(pv_[0]); pk.y = f2bf(pv_[1]); pk.z = f2bf(pv_[2]); pk.w = f2bf(pv_[3]);
          *reinterpret_cast<ushort4*>(
              &PwA[pwr_base + (((2 * n + (quad >> 1)) ^ fsw) << 3)]) = pk;
        }
      }
    }

    // PV: one bv load feeds both q-tiles (P is wave-local; LDS ops in-order per wave)
    {
      bf16x8 pB0 = *reinterpret_cast<const bf16x8*>(&PwB[pf0_off]);
      bf16x8 pB1 = *reinterpret_cast<const bf16x8*>(&PwB[pf1_off]);
      bf16x8 pA0, pA1;
      if (doA) {
        pA0 = *reinterpret_cast<const bf16x8*>(&PwA[pf0_off]);
        pA1 = *reinterpret_cast<const bf16x8*>(&PwA[pf1_off]);
      }
#pragma unroll
      for (int dt = 0; dt < 8; ++dt) {
        bf16x8 bv = *reinterpret_cast<const bf16x8*>(
            &Vts[cur][(dt * 16 + f) * 64 + ((quad ^ fsw) << 3)]);
        oB[dt] = __builtin_amdgcn_mfma_f32_16x16x32_bf16(pB0, bv, oB[dt], 0, 0, 0);
        if (doA)
          oA[dt] = __builtin_amdgcn_mfma_f32_16x16x32_bf16(pA0, bv, oA[dt], 0, 0, 0);
      }
#pragma unroll
      for (int dt = 0; dt < 8; ++dt) {
        bf16x8 bv = *reinterpret_cast<const bf16x8*>(
            &Vts[cur][(dt * 16 + f) * 64 + (((4 + quad) ^ fsw) << 3)]);
        oB[dt] = __builtin_amdgcn_mfma_f32_16x16x32_bf16(pB1, bv, oB[dt], 0, 0, 0);
        if (doA)
          oA[dt] = __builtin_amdgcn_mfma_f32_16x16x32_bf16(pA1, bv, oA[dt], 0, 0, 0);
      }
    }

    // staged tile landed (flew under compute); all waves done reading slot cur
    asm volatile("s_waitcnt vmcnt(0)" ::: "memory");
    __syncthreads();
    cur ^= 1;
  }

  // row-sum across quads (row f held by lanes f, f+16, f+32, f+48)
  lsA += __shfl_xor(lsA, 16); lsA += __shfl_xor(lsA, 32);
  lsB += __shfl_xor(lsB, 16); lsB += __shfl_xor(lsB, 32);
  const float invA = 1.0f / lsA, invB = 1.0f / lsB;

#pragma unroll
  for (int r = 0; r < 4; ++r) {
    const float linvA = __shfl(invA, quad * 4 + r);
    const float linvB = __shfl(invB, quad * 4 + r);
    const int sA = qtA * 64 + wv * 16 + quad * 4 + r;
    const int sB = qtB * 64 + wv * 16 + quad * 4 + r;
    const size_t growA = (size_t)b * S_LEN + sA;
    const size_t growB = (size_t)b * S_LEN + sB;
#pragma unroll
    for (int dt = 0; dt < 8; ++dt) {
      const int d = dt * 16 + f;
      const int col = h * 128 + d;
      const float gateA = bf2f(QKV[growA * DQKV + h * 256 + 128 + d]);
      const float valA = oA[dt][r] * linvA * (1.0f / (1.0f + __expf(-gateA)));
      ctxg[growA * 2048 + swz(col, (int)growA)] = f2bf(valA);
      const float gateB = bf2f(QKV[growB * DQKV + h * 256 + 128 + d]);
      const float valB = oB[dt][r] * linvB * (1.0f / (1.0f + __expf(-gateB)));
      ctxg[growB * 2048 + swz(col, (int)growB)] = f2bf(valB);
    }
  }
}

extern "C" void kernel_launch(void* const* d_in, const int* in_sizes, int n_in,
                              void* d_out, int out_size, void* d_ws, size_t ws_size,
                              hipStream_t stream) {
  const float* x    = (const float*)d_in[0];
  const float* Wq   = (const float*)d_in[1];
  const float* Wk   = (const float*)d_in[2];
  const float* Wv   = (const float*)d_in[3];
  const float* Wo   = (const float*)d_in[4];
  const float* qnw  = (const float*)d_in[5];
  const float* knw  = (const float*)d_in[6];
  const float* cosT = (const float*)d_in[7];
  const float* sinT = (const float*)d_in[8];
  // d_in[9] = mask (unused; causality computed analytically)

  char* p = (char*)d_ws;
  u16*   xb    = (u16*)p;  p += (size_t)NROWS * DIN * 2;       // x bf16 (swizzled)
  u16*   WqkvT = (u16*)p;  p += (size_t)DQKV * DIN * 2;        // [Wq|Wk|Wv]^T (swizzled)
  u16*   WoT   = (u16*)p;  p += (size_t)2048 * 2048 * 2;       // Wo^T (swizzled)
  u16*   QKVb  = (u16*)p;  p += (size_t)NROWS * DQKV * 2;      // qkv proj bf16 (plain)
  u16*   Qbf   = (u16*)p;  p += (size_t)2 * 16 * S_LEN * 128 * 2;
  u16*   Kbf   = (u16*)p;  p += (size_t)2 * 4 * S_LEN * 128 * 2;
  u16*   Vtb   = (u16*)p;  p += (size_t)2 * 4 * S_LEN * 128 * 2;
  u16*   ctxg  = (u16*)p;  p += (size_t)NROWS * 2048 * 2;      // gated ctx (swizzled)

  // 1 launch: x-cvt + all 4 weight transposes
  prep<<<22528, 256, 0, stream>>>(x, Wq, Wk, Wv, Wo, xb, WqkvT, WoT);

  // Q|gate projection: 8-phase 256x256 pipeline, grid 16x16 = 256 WGs
  gemm256<<<dim3(16, 16), 512, 0, stream>>>(xb, WqkvT, QKVb, DIN, DQKV);
  // K|V projection: 128^2 tile, grid 8x32 = 256 WGs
  gemm_bt<true><<<dim3(8, 32), 256, 0, stream>>>(
      xb, WqkvT + (size_t)4096 * 2048, QKVb + 4096, NROWS, 1024, DIN, DQKV);

  // 1 launch: qnorm_rope + knorm_rope + vtrans
  postproj<<<22528, 256, 0, stream>>>(QKVb, qnw, knw, cosT, sinT, Qbf, Kbf, Vtb);

  // paired-q attention: block (ip, bh) covers q-tiles ip and 31-ip in one sweep
  attn<<<dim3(16, 32), 256, 0, stream>>>(Qbf, Kbf, Vtb, QKVb, ctxg);

  gemm_bt<false><<<dim3(16, 32), 256, 0, stream>>>(ctxg, WoT, (float*)d_out, NROWS, 2048, 2048, 2048);
}

// Round 10
// 416.130 us; speedup vs baseline: 1.1820x; 1.1820x over previous
//
#include <hip/hip_runtime.h>

// Problem constants (B=2, S=2048, D_IN=2048, H=16, G=4, HD=128)
#define S_LEN 2048
#define NROWS 4096      // B*S
#define DIN   2048
#define DQKV  5120      // 4096 (q|gate) + 512 K + 512 V
#define DQG   4096

typedef __bf16 bf16x8 __attribute__((ext_vector_type(8)));
typedef float  floatx4 __attribute__((ext_vector_type(4)));
typedef unsigned short u16;

#define QK_SCALE 0.08838834764831845f   // 128^-0.5, folded into Q

__device__ __forceinline__ u16 f2bf(float f) {
  unsigned int u = __float_as_uint(f);
  u += 0x7fffu + ((u >> 16) & 1u);   // RNE
  return (u16)(u >> 16);
}
__device__ __forceinline__ float bf2f(u16 v) {
  return __uint_as_float(((unsigned int)v) << 16);
}
// XOR-8 chunk swizzle within each 64-element column group, keyed by row&7.
__device__ __forceinline__ int swz(int col, int row) {
  return (col & ~63) | ((((col >> 3) & 7) ^ (row & 7)) << 3) | (col & 7);
}

__device__ __forceinline__ void gload_lds16(const void* g, void* l) {
  __builtin_amdgcn_global_load_lds(
      (__attribute__((address_space(1))) void*)(void*)(g),
      (__attribute__((address_space(3))) void*)(l), 16, 0, 0);
}

// ---------------- merged preprocessing: x-cvt + 4 transposes (1 launch) ----------------
__device__ __forceinline__ void tcvt_body(const float* __restrict__ src,
                                          u16* __restrict__ dst,
                                          int C, int dld, int bx, int by,
                                          float (*tile)[33]) {
  const int c0 = bx * 32, r0 = by * 32;
  const int t = threadIdx.x;
  {
    const int rl = t >> 3, cl4 = (t & 7) * 4;
    const float4 v = *reinterpret_cast<const float4*>(src + (size_t)(r0 + rl) * C + c0 + cl4);
    tile[rl][cl4 + 0] = v.x; tile[rl][cl4 + 1] = v.y;
    tile[rl][cl4 + 2] = v.z; tile[rl][cl4 + 3] = v.w;
  }
  __syncthreads();
  {
    const int cl = t >> 3, rl4 = (t & 7) * 4;
    ushort4 o;
    o.x = f2bf(tile[rl4 + 0][cl]); o.y = f2bf(tile[rl4 + 1][cl]);
    o.z = f2bf(tile[rl4 + 2][cl]); o.w = f2bf(tile[rl4 + 3][cl]);
    const int rd = c0 + cl, cd = r0 + rl4;      // dst (row, col)
    *reinterpret_cast<ushort4*>(dst + (size_t)rd * dld + swz(cd, rd)) = o;
  }
}

__global__ __launch_bounds__(256) void prep(const float* __restrict__ x,
                                            const float* __restrict__ Wq,
                                            const float* __restrict__ Wk,
                                            const float* __restrict__ Wv,
                                            const float* __restrict__ Wo,
                                            u16* __restrict__ xb,
                                            u16* __restrict__ WqkvT,
                                            u16* __restrict__ WoT) {
  __shared__ float tile[32][33];
  const int bid = blockIdx.x;
  if (bid < 8192) {                       // cvt_x
    const int i = bid * 256 + threadIdx.x;
    const int row = i >> 9, col = (i & 511) << 2;
    const float4 v = reinterpret_cast<const float4*>(x)[i];
    ushort4 o;
    o.x = f2bf(v.x); o.y = f2bf(v.y); o.z = f2bf(v.z); o.w = f2bf(v.w);
    *reinterpret_cast<ushort4*>(xb + (size_t)row * DIN + swz(col, row)) = o;
  } else if (bid < 16384) {               // Wq^T (2048x4096 -> rows 0..4095)
    const int l = bid - 8192;
    tcvt_body(Wq, WqkvT, 4096, 2048, l & 127, l >> 7, tile);
  } else if (bid < 17408) {               // Wk^T -> rows 4096..4607
    const int l = bid - 16384;
    tcvt_body(Wk, WqkvT + (size_t)4096 * 2048, 512, 2048, l & 15, l >> 4, tile);
  } else if (bid < 18432) {               // Wv^T -> rows 4608..5119
    const int l = bid - 17408;
    tcvt_body(Wv, WqkvT + (size_t)4608 * 2048, 512, 2048, l & 15, l >> 4, tile);
  } else {                                // Wo^T
    const int l = bid - 18432;
    tcvt_body(Wo, WoT, 2048, 2048, l & 63, l >> 6, tile);
  }
}

// ---------------- bf16 GEMM, 128x128 tile, BK=64 (K|V proj + Wo GEMM) ----------------
template <bool BF16_OUT>
__global__ __launch_bounds__(256) void gemm_bt(const u16* __restrict__ A,
                                               const u16* __restrict__ Bt,
                                               void* __restrict__ Cv,
                                               int M, int N, int K, int ldc) {
  __shared__ __align__(16) u16 As[128 * 64];
  __shared__ __align__(16) u16 Bs[128 * 64];
  const int tid = threadIdx.x, wv = tid >> 6, lane = tid & 63;
  const int m0 = blockIdx.y * 128, n0 = blockIdx.x * 128;
  const int wm = (wv >> 1) * 64, wn = (wv & 1) * 64;
  const int frow = lane & 15, quad = lane >> 4, fsw = frow & 7;
  const int srow = lane >> 3, scol = (lane & 7) * 8;
  floatx4 acc[4][4] = {};
  for (int k0 = 0; k0 < K; k0 += 64) {
#pragma unroll
    for (int i = 0; i < 4; ++i) {
      const int rr = (wv * 4 + i) * 8;
      gload_lds16(A  + (size_t)(m0 + rr + srow) * K + k0 + scol, &As[rr * 64]);
      gload_lds16(Bt + (size_t)(n0 + rr + srow) * K + k0 + scol, &Bs[rr * 64]);
    }
    __syncthreads();
#pragma unroll
    for (int ks = 0; ks < 2; ++ks) {
      bf16x8 af[4], bfr[4];
#pragma unroll
      for (int mi = 0; mi < 4; ++mi)
        af[mi] = *reinterpret_cast<const bf16x8*>(
            &As[(wm + mi * 16 + frow) * 64 + (((ks * 4 + quad) ^ fsw) << 3)]);
#pragma unroll
      for (int ni = 0; ni < 4; ++ni)
        bfr[ni] = *reinterpret_cast<const bf16x8*>(
            &Bs[(wn + ni * 16 + frow) * 64 + (((ks * 4 + quad) ^ fsw) << 3)]);
#pragma unroll
      for (int mi = 0; mi < 4; ++mi)
#pragma unroll
        for (int ni = 0; ni < 4; ++ni)
          acc[mi][ni] = __builtin_amdgcn_mfma_f32_16x16x32_bf16(af[mi], bfr[ni], acc[mi][ni], 0, 0, 0);
    }
    __syncthreads();
  }
  const int crow = (lane >> 4) * 4, ccol = lane & 15;
#pragma unroll
  for (int mi = 0; mi < 4; ++mi)
#pragma unroll
    for (int ni = 0; ni < 4; ++ni) {
      const size_t base = (size_t)(m0 + wm + mi * 16 + crow) * ldc + (n0 + wn + ni * 16 + ccol);
      if constexpr (BF16_OUT) {
        u16* C = (u16*)Cv;
#pragma unroll
        for (int r = 0; r < 4; ++r) C[base + (size_t)r * ldc] = f2bf(acc[mi][ni][r]);
      } else {
        float* C = (float*)Cv;
#pragma unroll
        for (int r = 0; r < 4; ++r) C[base + (size_t)r * ldc] = acc[mi][ni][r];
      }
    }
}

// ---------------- 8-phase deep-pipelined bf16 GEMM, 256x256 tile, BK=64 ----------------
// (unchanged — 84 µs / 34% MfmaUtil measured; held constant)
__global__ __launch_bounds__(512, 2) void gemm256(const u16* __restrict__ A,
                                                  const u16* __restrict__ Bt,
                                                  u16* __restrict__ C,
                                                  int K, int ldc) {
  __shared__ __align__(16) u16 As[2][256 * 64];   // 64 KiB
  __shared__ __align__(16) u16 Bs[2][256 * 64];   // 64 KiB
  const int tid = threadIdx.x, wv = tid >> 6, lane = tid & 63;
  const int nx = gridDim.x;
  const int orig = blockIdx.y * nx + blockIdx.x;
  const int cpx = (nx * gridDim.y) >> 3;
  const int wgid = (orig & 7) * cpx + (orig >> 3);
  const int m0 = (wgid / nx) * 256, n0 = (wgid % nx) * 256;
  const int wm = (wv >> 2) * 128, wn = (wv & 3) * 64;
  const int f = lane & 15, quad = lane >> 4, fs = f & 7;

  const u16* Ab = A  + (size_t)(m0 + wv * 8 + (lane >> 3)) * K + (lane & 7) * 8;
  const u16* Bb = Bt + (size_t)(n0 + wv * 8 + (lane >> 3)) * K + (lane & 7) * 8;

  floatx4 acc[8][4] = {};
  bf16x8 af[4], bfr[4];

  auto stageA = [&](int sl, int t, int u) {
    gload_lds16(Ab + (size_t)u * 64 * K + (size_t)t * 64, &As[sl][(u * 64 + wv * 8) * 64]);
  };
  auto stageB = [&](int sl, int t, int u) {
    gload_lds16(Bb + (size_t)u * 64 * K + (size_t)t * 64, &Bs[sl][(u * 64 + wv * 8) * 64]);
  };
  auto loadA = [&](int sl, int fh, int ks) {
#pragma unroll
    for (int mf = 0; mf < 4; ++mf)
      af[mf] = *reinterpret_cast<const bf16x8*>(
          &As[sl][(wm + fh * 64 + mf * 16 + f) * 64 + ((((ks << 2) + quad) ^ fs) << 3)]);
  };
  auto loadB = [&](int sl, int ks) {
#pragma unroll
    for (int nf = 0; nf < 4; ++nf)
      bfr[nf] = *reinterpret_cast<const bf16x8*>(
          &Bs[sl][(wn + nf * 16 + f) * 64 + ((((ks << 2) + quad) ^ fs) << 3)]);
  };
  auto mmas = [&](int fh) {
#pragma unroll
    for (int mf = 0; mf < 4; ++mf)
#pragma unroll
      for (int nf = 0; nf < 4; ++nf)
        acc[fh * 4 + mf][nf] = __builtin_amdgcn_mfma_f32_16x16x32_bf16(
            af[mf], bfr[nf], acc[fh * 4 + mf][nf], 0, 0, 0);
  };

#pragma unroll
  for (int u = 0; u < 4; ++u) stageA(0, 0, u);
#pragma unroll
  for (int u = 0; u < 4; ++u) stageB(0, 0, u);
  stageA(1, 1, 0); stageA(1, 1, 2); stageB(1, 1, 0);
  asm volatile("s_waitcnt vmcnt(3)" ::: "memory");
  __builtin_amdgcn_s_barrier();

  const int IT = K >> 7;
#pragma unroll 1
  for (int i = 0; i < IT; ++i) {
    const int t0 = 2 * i;
    const bool st = (i < IT - 1);
    loadA(0, 0, 0); loadB(0, 0);
    stageA(1, t0 + 1, 1); stageA(1, t0 + 1, 3); stageB(1, t0 + 1, 1);
    __builtin_amdgcn_s_barrier();
    asm volatile("s_waitcnt lgkmcnt(0)" ::: "memory");
    __builtin_amdgcn_s_setprio(1); mmas(0); __builtin_amdgcn_s_setprio(0);
    __builtin_amdgcn_s_barrier();
    loadA(0, 1, 0);
    stageB(1, t0 + 1, 2); stageB(1, t0 + 1, 3);
    __builtin_amdgcn_s_barrier();
    asm volatile("s_waitcnt lgkmcnt(0)" ::: "memory");
    __builtin_amdgcn_s_setprio(1); mmas(1); __builtin_amdgcn_s_setprio(0);
    __builtin_amdgcn_s_barrier();
    loadA(0, 0, 1); loadB(0, 1);
    __builtin_amdgcn_s_barrier();
    asm volatile("s_waitcnt lgkmcnt(0)" ::: "memory");
    __builtin_amdgcn_s_setprio(1); mmas(0); __builtin_amdgcn_s_setprio(0);
    __builtin_amdgcn_s_barrier();
    loadA(0, 1, 1);
    if (st) { stageA(0, t0 + 2, 0); stageA(0, t0 + 2, 2); stageB(0, t0 + 2, 0); }
    __builtin_amdgcn_s_barrier();
    asm volatile("s_waitcnt lgkmcnt(0)" ::: "memory");
    __builtin_amdgcn_s_setprio(1); mmas(1); __builtin_amdgcn_s_setprio(0);
    if (st) { asm volatile("s_waitcnt vmcnt(3)" ::: "memory"); }
    else    { asm volatile("s_waitcnt vmcnt(0)" ::: "memory"); }
    __builtin_amdgcn_s_barrier();
    loadA(1, 0, 0); loadB(1, 0);
    if (st) { stageA(0, t0 + 2, 1); stageA(0, t0 + 2, 3); stageB(0, t0 + 2, 1); }
    __builtin_amdgcn_s_barrier();
    asm volatile("s_waitcnt lgkmcnt(0)" ::: "memory");
    __builtin_amdgcn_s_setprio(1); mmas(0); __builtin_amdgcn_s_setprio(0);
    __builtin_amdgcn_s_barrier();
    loadA(1, 1, 0);
    if (st) { stageB(0, t0 + 2, 2); stageB(0, t0 + 2, 3); }
    __builtin_amdgcn_s_barrier();
    asm volatile("s_waitcnt lgkmcnt(0)" ::: "memory");
    __builtin_amdgcn_s_setprio(1); mmas(1); __builtin_amdgcn_s_setprio(0);
    __builtin_amdgcn_s_barrier();
    loadA(1, 0, 1); loadB(1, 1);
    __builtin_amdgcn_s_barrier();
    asm volatile("s_waitcnt lgkmcnt(0)" ::: "memory");
    __builtin_amdgcn_s_setprio(1); mmas(0); __builtin_amdgcn_s_setprio(0);
    __builtin_amdgcn_s_barrier();
    loadA(1, 1, 1);
    if (st) { stageA(1, t0 + 3, 0); stageA(1, t0 + 3, 2); stageB(1, t0 + 3, 0); }
    __builtin_amdgcn_s_barrier();
    asm volatile("s_waitcnt lgkmcnt(0)" ::: "memory");
    __builtin_amdgcn_s_setprio(1); mmas(1); __builtin_amdgcn_s_setprio(0);
    if (st) { asm volatile("s_waitcnt vmcnt(3)" ::: "memory"); }
    __builtin_amdgcn_s_barrier();
  }

#pragma unroll
  for (int mf = 0; mf < 8; ++mf)
#pragma unroll
    for (int nf = 0; nf < 4; ++nf) {
      const size_t base = (size_t)(m0 + wm + (mf >> 2) * 64 + (mf & 3) * 16 + quad * 4) * ldc
                        + (n0 + wn + nf * 16 + f);
#pragma unroll
      for (int r = 0; r < 4; ++r) C[base + (size_t)r * ldc] = f2bf(acc[mf][nf][r]);
    }
}

// ---------------- merged post-projection: qnorm_rope + knorm_rope + vtrans (1 launch) ----------------
__global__ __launch_bounds__(256) void postproj(const u16* __restrict__ QKV,
                                                const float* __restrict__ qw,
                                                const float* __restrict__ kw,
                                                const float* __restrict__ cosT,
                                                const float* __restrict__ sinT,
                                                u16* __restrict__ Qb,
                                                u16* __restrict__ Kb,
                                                u16* __restrict__ Vt) {
  __shared__ u16 tile[32][40];
  const int bid = blockIdx.x;
  const int wv = threadIdx.x >> 6, lane = threadIdx.x & 63;
  if (bid < 16384) {                      // qnorm_rope
    const int idx = bid * 4 + wv;
    const int h = idx & 15, row = idx >> 4;
    const int s = row & (S_LEN - 1), b = row >> 11;
    const u16* base = QKV + (size_t)row * DQKV + h * 256;
    const float v0 = bf2f(base[lane]), v1 = bf2f(base[lane + 64]);
    float ss = v0 * v0 + v1 * v1;
#pragma unroll
    for (int m = 32; m >= 1; m >>= 1) ss += __shfl_xor(ss, m);
    const float rn = rsqrtf(ss * (1.0f / 128.0f) + 1e-6f) * QK_SCALE;
    const float n0 = v0 * rn * (1.0f + qw[lane]);
    const float n1 = v1 * rn * (1.0f + qw[lane + 64]);
    const float c0 = cosT[(size_t)s * 128 + lane], c1 = cosT[(size_t)s * 128 + lane + 64];
    const float sn0 = sinT[(size_t)s * 128 + lane], sn1 = sinT[(size_t)s * 128 + lane + 64];
    u16* qb = Qb + ((size_t)(b * 16 + h) * S_LEN + s) * 128;
    qb[lane]      = f2bf(n0 * c0 - n1 * sn0);
    qb[lane + 64] = f2bf(n1 * c1 + n0 * sn1);
  } else if (bid < 20480) {               // knorm_rope
    const int idx = (bid - 16384) * 4 + wv;
    const int g = idx & 3, row = idx >> 2;
    const int s = row & (S_LEN - 1), b = row >> 11;
    const u16* base = QKV + (size_t)row * DQKV + DQG + g * 128;
    const float v0 = bf2f(base[lane]), v1 = bf2f(base[lane + 64]);
    float ss = v0 * v0 + v1 * v1;
#pragma unroll
    for (int m = 32; m >= 1; m >>= 1) ss += __shfl_xor(ss, m);
    const float rn = rsqrtf(ss * (1.0f / 128.0f) + 1e-6f);
    const float n0 = v0 * rn * (1.0f + kw[lane]);
    const float n1 = v1 * rn * (1.0f + kw[lane + 64]);
    const float c0 = cosT[(size_t)s * 128 + lane], c1 = cosT[(size_t)s * 128 + lane + 64];
    const float sn0 = sinT[(size_t)s * 128 + lane], sn1 = sinT[(size_t)s * 128 + lane + 64];
    u16* kb = Kb + ((size_t)(b * 4 + g) * S_LEN + s) * 128;
    const int sw = s & 7;
    const int d0 = lane, d1 = lane + 64;
    const int p0 = (((d0 >> 3) ^ sw) << 3) | (d0 & 7);
    const int p1 = (((d1 >> 3) ^ sw) << 3) | (d1 & 7);
    kb[p0] = f2bf(n0 * c0 - n1 * sn0);
    kb[p1] = f2bf(n1 * c1 + n0 * sn1);
  } else {                                // vtrans
    const int l = bid - 20480;
    const int bg = l >> 8, rem = l & 255;
    const int d0 = ((rem >> 6) & 3) * 32, s0 = (rem & 63) * 32;
    const int b = bg >> 2, g = bg & 3;
    const int t = threadIdx.x;
    {
      const int sl = t >> 3, dl4 = (t & 7) * 4;
      const ushort4 v = *reinterpret_cast<const ushort4*>(
          QKV + (size_t)(b * S_LEN + s0 + sl) * DQKV + DQG + 512 + g * 128 + d0 + dl4);
      tile[sl][dl4 + 0] = v.x; tile[sl][dl4 + 1] = v.y;
      tile[sl][dl4 + 2] = v.z; tile[sl][dl4 + 3] = v.w;
    }
    __syncthreads();
    {
      const int dl = t >> 3, sl4 = (t & 7) * 4;
      ushort4 o;
      o.x = tile[sl4 + 0][dl]; o.y = tile[sl4 + 1][dl];
      o.z = tile[sl4 + 2][dl]; o.w = tile[sl4 + 3][dl];
      const int d = d0 + dl, s = s0 + sl4;
      const size_t base = (size_t)(bg * 128 + d) * S_LEN + (s & ~63);
      const int pos = ((((s >> 3) & 7) ^ (d & 7)) << 3) | (s & 7);
      *reinterpret_cast<ushort4*>(Vt + base + pos) = o;
    }
  }
}

// ---------------- MFMA flash attention + gating (swapped QK^T, 4 blocks/CU) ----------------
// One q-tile per block; grid (32,32) = 1024 blocks -> 4 blocks/CU co-resident
// (rounds 5-8 were grid-capped at 2/CU; round 9 showed occupancy is THE lever).
// Single-buffered K/V + swizzled P = 40960 B LDS exactly -> 4 blocks/CU.
// Exposed per-tile staging latency is hidden by cross-block TLP (16 waves/CU).
// Work balance: qt = (ip&1) ? ip>>1 : 31-(ip>>1) -- bijective on 0..31, any
// contiguous dispatch window has ~equal total work.
__global__ __launch_bounds__(256) void attn(const u16* __restrict__ Qb,
                                            const u16* __restrict__ Kb,
                                            const u16* __restrict__ Vt,
                                            const u16* __restrict__ QKV,
                                            u16* __restrict__ ctxg) {
  __shared__ __align__(16) u16 Ks[64 * 128];   // [key][d], chunk-swizzled (16 KB)
  __shared__ __align__(16) u16 Vts[128 * 64];  // [d][key], chunk-swizzled (16 KB)
  __shared__ __align__(16) u16 Ps[4][16 * 64]; // per-wave P [q=f][key] (8 KB)
  const int tid = threadIdx.x, wv = tid >> 6, lane = tid & 63;
  const int ip = blockIdx.x, bh = blockIdx.y;
  const int qt = (ip & 1) ? (ip >> 1) : 31 - (ip >> 1);
  const int b = bh >> 4, h = bh & 15, g = h >> 2, bg = b * 4 + g;
  const int f = lane & 15, quad = lane >> 4, fq = quad * 8;
  const int fsw = f & 7;
  const u16* Kp = Kb + (size_t)bg * S_LEN * 128;
  const u16* Vp = Vt + (size_t)bg * 128 * S_LEN;
  u16* Pw = Ps[wv];
  const int pwr_base = f * 64 + ((quad & 1) << 2);
  const int pf0_off = f * 64 + ((quad ^ fsw) << 3);
  const int pf1_off = f * 64 + (((4 + quad) ^ fsw) << 3);

  const int nkt = qt + 1;
  const int qrow = qt * 64 + wv * 16 + f;
  const u16* Qp = Qb + ((size_t)bh * S_LEN + qt * 64 + wv * 16) * 128;
  bf16x8 aq[4];
#pragma unroll
  for (int c = 0; c < 4; ++c)
    aq[c] = *reinterpret_cast<const bf16x8*>(&Qp[(size_t)f * 128 + c * 32 + fq]);

  floatx4 o[8] = {};
  float lsum = 0.f;

  for (int t = 0; t < nkt; ++t) {
    const int kb = t * 64;
    // stage tile t (single buffer; prev compute sealed by end-of-loop barrier)
    {
      const int k0 = kb;
#pragma unroll
      for (int i = 0; i < 4; ++i) {
        const int j = wv * 4 + i;
        gload_lds16(Kp + (size_t)k0 * 128 + j * 512 + lane * 8, &Ks[j * 512]);
      }
#pragma unroll
      for (int i = 0; i < 4; ++i) {
        const int r0 = (wv * 4 + i) * 8;
        gload_lds16(Vp + (size_t)(r0 + (lane >> 3)) * S_LEN + k0 + (lane & 7) * 8,
                    &Vts[r0 * 64]);
      }
    }
    asm volatile("s_waitcnt vmcnt(0)" ::: "memory");
    __syncthreads();

    // QK^T (swapped: lane (quad,f) holds P[q=f][key=kb+n*16+quad*4+r])
    floatx4 sc[4] = {};
#pragma unroll
    for (int c = 0; c < 4; ++c)
#pragma unroll
      for (int n = 0; n < 4; ++n) {
        bf16x8 bk = *reinterpret_cast<const bf16x8*>(
            &Ks[(n * 16 + f) * 128 + (((4 * c + quad) ^ fsw) << 3)]);
        sc[n] = __builtin_amdgcn_mfma_f32_16x16x32_bf16(bk, aq[c], sc[n], 0, 0, 0);
      }

    // softmax + b64 P store
#pragma unroll
    for (int n = 0; n < 4; ++n) {
      float pv_[4];
#pragma unroll
      for (int r = 0; r < 4; ++r) {
        const int key = kb + n * 16 + quad * 4 + r;
        const float p = (key <= qrow) ? __expf(sc[n][r]) : 0.f;
        lsum += p; pv_[r] = p;
      }
      ushort4 pk;
      pk.x = f2bf(pv_[0]); pk.y = f2bf(pv_[1]); pk.z = f2bf(pv_[2]); pk.w = f2bf(pv_[3]);
      *reinterpret_cast<ushort4*>(
          &Pw[pwr_base + (((2 * n + (quad >> 1)) ^ fsw) << 3)]) = pk;
    }

    // PV (P wave-local; LDS ops in-order per wave)
    bf16x8 pf0 = *reinterpret_cast<const bf16x8*>(&Pw[pf0_off]);
    bf16x8 pf1 = *reinterpret_cast<const bf16x8*>(&Pw[pf1_off]);
#pragma unroll
    for (int dt = 0; dt < 8; ++dt) {
      bf16x8 bv = *reinterpret_cast<const bf16x8*>(
          &Vts[(dt * 16 + f) * 64 + ((quad ^ fsw) << 3)]);
      o[dt] = __builtin_amdgcn_mfma_f32_16x16x32_bf16(pf0, bv, o[dt], 0, 0, 0);
    }
#pragma unroll
    for (int dt = 0; dt < 8; ++dt) {
      bf16x8 bv = *reinterpret_cast<const bf16x8*>(
          &Vts[(dt * 16 + f) * 64 + (((4 + quad) ^ fsw) << 3)]);
      o[dt] = __builtin_amdgcn_mfma_f32_16x16x32_bf16(pf1, bv, o[dt], 0, 0, 0);
    }
    __syncthreads();   // all waves done with Ks/Vts before next stage
  }

  // row-sum across quads (row f held by lanes f, f+16, f+32, f+48)
  lsum += __shfl_xor(lsum, 16);
  lsum += __shfl_xor(lsum, 32);
  const float inv = 1.0f / lsum;

  // epilogue: rows quad*4+r; row sums keyed by f -> broadcast from lanes 0..15
#pragma unroll
  for (int r = 0; r < 4; ++r) {
    const float linv = __shfl(inv, quad * 4 + r);
    const int s = qt * 64 + wv * 16 + quad * 4 + r;
    const size_t grow = (size_t)b * S_LEN + s;
#pragma unroll
    for (int dt = 0; dt < 8; ++dt) {
      const int d = dt * 16 + f;
      const float gate = bf2f(QKV[grow * DQKV + h * 256 + 128 + d]);
      const float val = o[dt][r] * linv * (1.0f / (1.0f + __expf(-gate)));
      const int col = h * 128 + d;
      ctxg[grow * 2048 + swz(col, (int)grow)] = f2bf(val);
    }
  }
}

extern "C" void kernel_launch(void* const* d_in, const int* in_sizes, int n_in,
                              void* d_out, int out_size, void* d_ws, size_t ws_size,
                              hipStream_t stream) {
  const float* x    = (const float*)d_in[0];
  const float* Wq   = (const float*)d_in[1];
  const float* Wk   = (const float*)d_in[2];
  const float* Wv   = (const float*)d_in[3];
  const float* Wo   = (const float*)d_in[4];
  const float* qnw  = (const float*)d_in[5];
  const float* knw  = (const float*)d_in[6];
  const float* cosT = (const float*)d_in[7];
  const float* sinT = (const float*)d_in[8];
  // d_in[9] = mask (unused; causality computed analytically)

  char* p = (char*)d_ws;
  u16*   xb    = (u16*)p;  p += (size_t)NROWS * DIN * 2;       // x bf16 (swizzled)
  u16*   WqkvT = (u16*)p;  p += (size_t)DQKV * DIN * 2;        // [Wq|Wk|Wv]^T (swizzled)
  u16*   WoT   = (u16*)p;  p += (size_t)2048 * 2048 * 2;       // Wo^T (swizzled)
  u16*   QKVb  = (u16*)p;  p += (size_t)NROWS * DQKV * 2;      // qkv proj bf16 (plain)
  u16*   Qbf   = (u16*)p;  p += (size_t)2 * 16 * S_LEN * 128 * 2;
  u16*   Kbf   = (u16*)p;  p += (size_t)2 * 4 * S_LEN * 128 * 2;
  u16*   Vtb   = (u16*)p;  p += (size_t)2 * 4 * S_LEN * 128 * 2;
  u16*   ctxg  = (u16*)p;  p += (size_t)NROWS * 2048 * 2;      // gated ctx (swizzled)

  // 1 launch: x-cvt + all 4 weight transposes
  prep<<<22528, 256, 0, stream>>>(x, Wq, Wk, Wv, Wo, xb, WqkvT, WoT);

  // Q|gate projection: 8-phase 256x256 pipeline, grid 16x16 = 256 WGs
  gemm256<<<dim3(16, 16), 512, 0, stream>>>(xb, WqkvT, QKVb, DIN, DQKV);
  // K|V projection: 128^2 tile, grid 8x32 = 256 WGs
  gemm_bt<true><<<dim3(8, 32), 256, 0, stream>>>(
      xb, WqkvT + (size_t)4096 * 2048, QKVb + 4096, NROWS, 1024, DIN, DQKV);

  // 1 launch: qnorm_rope + knorm_rope + vtrans
  postproj<<<22528, 256, 0, stream>>>(QKVb, qnw, knw, cosT, sinT, Qbf, Kbf, Vtb);

  // one q-tile per block, 1024 blocks = 4/CU; balanced qt mapping
  attn<<<dim3(32, 32), 256, 0, stream>>>(Qbf, Kbf, Vtb, QKVb, ctxg);

  gemm_bt<false><<<dim3(16, 32), 256, 0, stream>>>(ctxg, WoT, (float*)d_out, NROWS, 2048, 2048, 2048);
}